// Round 23
// baseline (104.469 us; speedup 1.0000x reference)
//
#include <hip/hip_runtime.h>

#define HDIM   256
#define NTYPE  100
#define CAP    8      // max crystals per block (span of ~489 atoms ~= 5)
#define SH2    132    // LDS h-row stride in uints (128 data + 4 pad)
#define THREADS 256
#define SLOT8  66
#define REG8   (32 * SLOT8)
#define SLOT4  34

typedef float f32x4_n __attribute__((ext_vector_type(4)));
typedef _Float16 h2_t __attribute__((ext_vector_type(2)));
union H2U { unsigned u; h2_t h; };

#define LD4(p) (*(const float4*)(p))

__device__ __forceinline__ float silu_f(float x) {
    return x / (1.0f + __expf(-x));
}

__device__ __forceinline__ float fdot2u(unsigned a, unsigned b, float c) {
    H2U x, y; x.u = a; y.u = b;
    return __builtin_amdgcn_fdot2(x.h, y.h, c, false);
}

__device__ __forceinline__ unsigned packh2(float a, float b) {
    H2U u; u.h = (h2_t){(_Float16)a, (_Float16)b}; return u.u;
}

// pack k-paired f16, n-contiguous: out[k2*ld + n] = (w[2k2][n], w[2k2+1][n])
// p1[128][256] | p2[128][256] | phd[128][256] (wc1 cols 0-127, wl1 128-255)
// | pt[128][128] (wt cols 0-99, zero-pad)
#define NW_TOT 114688
__global__ __launch_bounds__(256) void prep_kernel(
    const float* __restrict__ w1a, const float* __restrict__ w2a,
    const float* __restrict__ wt,  const float* __restrict__ wc1,
    const float* __restrict__ wl1, unsigned* __restrict__ outw)
{
    const int stride = gridDim.x * blockDim.x;
    for (int i = blockIdx.x * blockDim.x + threadIdx.x; i < NW_TOT; i += stride) {
        float v0, v1;
        if (i < 32768) {
            int k2 = i >> 8, n = i & 255;
            v0 = w1a[(size_t)(2 * k2) * 256 + n]; v1 = w1a[(size_t)(2 * k2 + 1) * 256 + n];
        } else if (i < 65536) {
            int t = i - 32768; int k2 = t >> 8, n = t & 255;
            v0 = w2a[(size_t)(2 * k2) * 256 + n]; v1 = w2a[(size_t)(2 * k2 + 1) * 256 + n];
        } else if (i < 98304) {
            int t = i - 65536; int k2 = t >> 8, n = t & 255;
            const float* s = (n < 128) ? wc1 : wl1;
            int nn = n & 127;
            v0 = s[(size_t)(2 * k2) * 128 + nn]; v1 = s[(size_t)(2 * k2 + 1) * 128 + nn];
        } else {
            int t = i - 98304; int k2 = t >> 7, n = t & 127;
            if (n < NTYPE) { v0 = wt[(size_t)(2 * k2) * NTYPE + n]; v1 = wt[(size_t)(2 * k2 + 1) * NTYPE + n]; }
            else { v0 = 0.f; v1 = 0.f; }
        }
        outw[i] = packh2(v0, v1);
    }
}

// 8 rows x 8 cols (lo j0, hi j0+128) over 16 k2 (ksg slice). ld = 256 uints.
__device__ __forceinline__ void gemm8x8(
    const unsigned* hb, const unsigned* __restrict__ W,
    const int kbase, const int j0, float* acc /*64*/)
{
#pragma unroll
    for (int ch = 0; ch < 4; ++ch) {
        uint4 h[8];
#pragma unroll
        for (int r = 0; r < 8; ++r) h[r] = *(const uint4*)&hb[r * SH2 + ch * 4];
#pragma unroll
        for (int kk = 0; kk < 4; ++kk) {
            const unsigned* w = W + (size_t)(kbase + ch * 4 + kk) * 256 + j0;
            uint4 wl = *(const uint4*)w;
            uint4 wh = *(const uint4*)(w + 128);
#pragma unroll
            for (int r = 0; r < 8; ++r) {
                unsigned hv = (kk == 0) ? h[r].x : (kk == 1) ? h[r].y : (kk == 2) ? h[r].z : h[r].w;
                acc[r*8+0] = fdot2u(hv, wl.x, acc[r*8+0]);
                acc[r*8+1] = fdot2u(hv, wl.y, acc[r*8+1]);
                acc[r*8+2] = fdot2u(hv, wl.z, acc[r*8+2]);
                acc[r*8+3] = fdot2u(hv, wl.w, acc[r*8+3]);
                acc[r*8+4] = fdot2u(hv, wh.x, acc[r*8+4]);
                acc[r*8+5] = fdot2u(hv, wh.y, acc[r*8+5]);
                acc[r*8+6] = fdot2u(hv, wh.z, acc[r*8+6]);
                acc[r*8+7] = fdot2u(hv, wh.w, acc[r*8+7]);
            }
        }
    }
}

// 8 rows x 4 cols over 16 k2. ld = 128 uints (pt).
__device__ __forceinline__ void gemm8x4(
    const unsigned* hb, const unsigned* __restrict__ W,
    const int kbase, const int j0, float* acc /*32*/)
{
#pragma unroll
    for (int ch = 0; ch < 4; ++ch) {
        uint4 h[8];
#pragma unroll
        for (int r = 0; r < 8; ++r) h[r] = *(const uint4*)&hb[r * SH2 + ch * 4];
#pragma unroll
        for (int kk = 0; kk < 4; ++kk) {
            const unsigned* w = W + (size_t)(kbase + ch * 4 + kk) * 128 + j0;
            uint4 wl = *(const uint4*)w;
#pragma unroll
            for (int r = 0; r < 8; ++r) {
                unsigned hv = (kk == 0) ? h[r].x : (kk == 1) ? h[r].y : (kk == 2) ? h[r].z : h[r].w;
                acc[r*4+0] = fdot2u(hv, wl.x, acc[r*4+0]);
                acc[r*4+1] = fdot2u(hv, wl.y, acc[r*4+1]);
                acc[r*4+2] = fdot2u(hv, wl.z, acc[r*4+2]);
                acc[r*4+3] = fdot2u(hv, wl.w, acc[r*4+3]);
            }
        }
    }
}

template<int NV>
__device__ __forceinline__ void shfl_red(float* a) {
#pragma unroll
    for (int i = 0; i < NV; ++i) a[i] += __shfl_xor(a[i], 32);
}

// cross-wave reduce of NV floats/thread (col-group cg owns slot). After return,
// threads tid<32 hold the full sums. Includes trailing barrier-safety for reuse.
template<int NV, int SLOT>
__device__ __forceinline__ void block_red(float* a, float* red, int tid, int cg,
                                          int wv, bool lo_h)
{
    shfl_red<NV>(a);
    if (wv && lo_h) {
        float* rp = &red[(wv - 1) * REG8 + cg * SLOT];
#pragma unroll
        for (int i = 0; i < NV; ++i) rp[i] = a[i];
    }
    __syncthreads();
    if (tid < 32) {
#pragma unroll
        for (int p = 0; p < 3; ++p) {
            const float* rp = &red[p * REG8 + cg * SLOT];
#pragma unroll
            for (int i = 0; i < NV; ++i) a[i] += rp[i];
        }
    }
}

// One block = one atom chunk (~489 atoms -> ~5 crystals). Computes its crystals'
// tables locally, then streams its own atoms. Blocks desync -> compute hides
// under the chip-wide write stream.
__global__ __launch_bounds__(THREADS, 4) void fused_kernel(
    const int* __restrict__ batch, int N,
    const float* __restrict__ t_emb,
    const unsigned* __restrict__ wpk,
    const float* __restrict__ b1a, const float* __restrict__ b2a,
    const float* __restrict__ bc1, const float* __restrict__ bl1,
    const float* __restrict__ wc2, const float* __restrict__ bc2,
    const float* __restrict__ wl2, const float* __restrict__ bl2,
    const float* __restrict__ bt,
    float* __restrict__ out_coord,    // [N,3]
    float* __restrict__ cell_out,     // [B,6]
    f32x4_n* __restrict__ out_logits4)// [N,25] f4
{
    const unsigned* p1  = wpk;
    const unsigned* p2  = wpk + 32768;
    const unsigned* phd = wpk + 65536;
    const unsigned* pt  = wpk + 98304;

    __shared__ unsigned bufA[CAP * SH2];   // h0 / h (f16 pairs)
    __shared__ unsigned bufB[CAP * SH2];   // h1 / gc|gl
    __shared__ float red[3 * REG8];        // 25.3 KB
    __shared__ float logits_s[CAP * 104];
    __shared__ float coord_s[CAP * 4];
    __shared__ int   lb_s[CAP + 1];
    __shared__ float cnt_s[CAP];
    __shared__ int   hdr[2];               // c0, nc

    const int tid = threadIdx.x;
    const int CHn = (N + 1023) / 1024;
    const int a0  = blockIdx.x * CHn;
    if (a0 >= N) return;
    const int a1  = min(a0 + CHn, N);

    if (tid == 0) {
        int c0v = batch[a0];
        int c1v = batch[a1 - 1];
        hdr[0] = c0v;
        hdr[1] = min(c1v - c0v + 1, CAP);
    }
    __syncthreads();
    const int c0 = hdr[0], nc = hdr[1];

    // lb bounds for crystals c0..c0+nc
    if (tid <= nc) {
        int v = c0 + tid;
        int lo = 0, hi = N;
        while (lo < hi) { int mid = (lo + hi) >> 1; if (batch[mid] < v) lo = mid + 1; else hi = mid; }
        lb_s[tid] = lo;
    }
    // stage t_emb rows -> f16 (rows >= nc zeroed)
    {
        int r = tid >> 5, q = tid & 31;
        uint4 hv = make_uint4(0, 0, 0, 0);
        if (r < nc) {
            float4 v0 = LD4(&t_emb[(size_t)(c0 + r) * HDIM + q * 8]);
            float4 v1 = LD4(&t_emb[(size_t)(c0 + r) * HDIM + q * 8 + 4]);
            hv = make_uint4(packh2(v0.x, v0.y), packh2(v0.z, v0.w),
                            packh2(v1.x, v1.y), packh2(v1.z, v1.w));
        }
        *(uint4*)&bufA[r * SH2 + q * 4] = hv;
    }
    __syncthreads();
    if (tid < nc) cnt_s[tid] = (float)(lb_s[tid + 1] - lb_s[tid]);

    const int cg  = tid & 31, j0 = cg * 4;
    const int ksg = tid >> 5;
    const int wv  = tid >> 6;
    const bool lo_h = !(tid & 32);

    float acc[64];

    // ---------------- L1: h1 = silu(h0 @ w1a + b1a)   bufA -> bufB
#pragma unroll
    for (int i = 0; i < 64; ++i) acc[i] = 0.f;
    gemm8x8(&bufA[ksg * 16], p1, ksg * 16, j0, acc);
    block_red<64, SLOT8>(acc, red, tid, cg, wv, lo_h);
    if (tid < 32) {
        float4 bl = LD4(b1a + j0), bh = LD4(b1a + j0 + 128);
        const float bb[8] = {bl.x, bl.y, bl.z, bl.w, bh.x, bh.y, bh.z, bh.w};
#pragma unroll
        for (int r = 0; r < 8; ++r) {
            float v[8];
#pragma unroll
            for (int c = 0; c < 8; ++c) v[c] = silu_f(acc[r*8+c] + bb[c]);
            *(uint2*)&bufB[r * SH2 + cg * 2]      = make_uint2(packh2(v[0], v[1]), packh2(v[2], v[3]));
            *(uint2*)&bufB[r * SH2 + 64 + cg * 2] = make_uint2(packh2(v[4], v[5]), packh2(v[6], v[7]));
        }
    }
    __syncthreads();

    // ---------------- L2: h = h1 @ w2a + b2a          bufB -> bufA
#pragma unroll
    for (int i = 0; i < 64; ++i) acc[i] = 0.f;
    gemm8x8(&bufB[ksg * 16], p2, ksg * 16, j0, acc);
    block_red<64, SLOT8>(acc, red, tid, cg, wv, lo_h);
    if (tid < 32) {
        float4 bl = LD4(b2a + j0), bh = LD4(b2a + j0 + 128);
        const float bb[8] = {bl.x, bl.y, bl.z, bl.w, bh.x, bh.y, bh.z, bh.w};
#pragma unroll
        for (int r = 0; r < 8; ++r) {
            float v[8];
#pragma unroll
            for (int c = 0; c < 8; ++c) v[c] = acc[r*8+c] + bb[c];
            *(uint2*)&bufA[r * SH2 + cg * 2]      = make_uint2(packh2(v[0], v[1]), packh2(v[2], v[3]));
            *(uint2*)&bufA[r * SH2 + 64 + cg * 2] = make_uint2(packh2(v[4], v[5]), packh2(v[6], v[7]));
        }
    }
    __syncthreads();

    // ---------------- HEADS: gc cols 0-127 | gl cols 128-255   bufA -> bufB
#pragma unroll
    for (int i = 0; i < 64; ++i) acc[i] = 0.f;
    gemm8x8(&bufA[ksg * 16], phd, ksg * 16, j0, acc);
    block_red<64, SLOT8>(acc, red, tid, cg, wv, lo_h);
    if (tid < 32) {
        float4 bcv = LD4(bc1 + j0), blv = LD4(bl1 + j0);
        const float bc_[4] = {bcv.x, bcv.y, bcv.z, bcv.w};
        const float bl_[4] = {blv.x, blv.y, blv.z, blv.w};
#pragma unroll
        for (int r = 0; r < 8; ++r) {
            float vc[4], vg[4];
#pragma unroll
            for (int c = 0; c < 4; ++c) {
                vc[c] = silu_f(acc[r*8+c] + bc_[c]);
                vg[c] = silu_f(acc[r*8+4+c] * cnt_s[r] + bl_[c]);
            }
            *(uint2*)&bufB[r * SH2 + cg * 2]      = make_uint2(packh2(vc[0], vc[1]), packh2(vc[2], vc[3]));
            *(uint2*)&bufB[r * SH2 + 64 + cg * 2] = make_uint2(packh2(vg[0], vg[1]), packh2(vg[2], vg[3]));
        }
    }
    __syncthreads();

    // ---------------- LOGITS: h @ wt + bt -> logits_s
    {
        float la[32];
#pragma unroll
        for (int i = 0; i < 32; ++i) la[i] = 0.f;
        gemm8x4(&bufA[ksg * 16], pt, ksg * 16, j0, la);
        block_red<32, SLOT4>(la, red, tid, cg, wv, lo_h);
        if (tid < 32 && j0 < NTYPE) {
            float4 b4 = LD4(bt + j0);
#pragma unroll
            for (int r = 0; r < 8; ++r) {
                *(float4*)&logits_s[r * 104 + j0] =
                    make_float4(la[r*4+0] + b4.x, la[r*4+1] + b4.y,
                                la[r*4+2] + b4.z, la[r*4+3] + b4.w);
            }
        }
        __syncthreads();
    }

    // ---------------- tiny heads (coord -> coord_s; cell -> global, dup-safe)
    if (tid < nc * 3) {
        int r = tid / 3, c = tid - 3 * r;
        float a = 0.f;
#pragma unroll 8
        for (int k2 = 0; k2 < 64; ++k2) {
            H2U u; u.u = bufB[r * SH2 + k2];
            a += (float)u.h.x * wc2[(2 * k2) * 3 + c] + (float)u.h.y * wc2[(2 * k2 + 1) * 3 + c];
        }
        coord_s[r * 4 + c] = a + bc2[c];
    } else if (tid >= 64 && tid < 64 + nc * 6) {
        int t2 = tid - 64;
        int r = t2 / 6, c = t2 - 6 * r;
        float a = 0.f;
#pragma unroll 8
        for (int k2 = 0; k2 < 64; ++k2) {
            H2U u; u.u = bufB[r * SH2 + 64 + k2];
            a += (float)u.h.x * wl2[(2 * k2) * 6 + c] + (float)u.h.y * wl2[(2 * k2 + 1) * 6 + c];
        }
        cell_out[(size_t)(c0 + r) * 6 + c] = a + bl2[c];
    }
    __syncthreads();

    // ---------------- stream own atoms (coalesced nontemporal)
    const int na = a1 - a0;
    {
        const int tot = na * 25;
        for (int t = tid; t < tot; t += THREADS) {
            int ai = t / 25, q = t - 25 * ai;
            int atom = a0 + ai;
            int r = batch[atom] - c0;
            f32x4_n v = *(const f32x4_n*)&logits_s[r * 104 + q * 4];
            __builtin_nontemporal_store(v, &out_logits4[(size_t)atom * 25 + q]);
        }
        const int tot3 = na * 3;
        float* oc = out_coord + (size_t)a0 * 3;
        for (int t = tid; t < tot3; t += THREADS) {
            int ai = t / 3, c = t - 3 * ai;
            int r = batch[a0 + ai] - c0;
            __builtin_nontemporal_store(coord_s[r * 4 + c], &oc[t]);
        }
    }
}

extern "C" void kernel_launch(void* const* d_in, const int* in_sizes, int n_in,
                              void* d_out, int out_size, void* d_ws, size_t ws_size,
                              hipStream_t stream)
{
    const int*   batch = (const int*)d_in[1];
    const float* t_emb = (const float*)d_in[3];
    const float* w1a = (const float*)d_in[4];
    const float* b1a = (const float*)d_in[5];
    const float* w2a = (const float*)d_in[6];
    const float* b2a = (const float*)d_in[7];
    const float* wc1 = (const float*)d_in[8];
    const float* bc1 = (const float*)d_in[9];
    const float* wc2 = (const float*)d_in[10];
    const float* bc2 = (const float*)d_in[11];
    const float* wl1 = (const float*)d_in[12];
    const float* bl1 = (const float*)d_in[13];
    const float* wl2 = (const float*)d_in[14];
    const float* bl2 = (const float*)d_in[15];
    const float* wt  = (const float*)d_in[16];
    const float* bt  = (const float*)d_in[17];

    const int N = in_sizes[1];        // 500000
    const int B = in_sizes[2] / 9;    // 4096

    float* out        = (float*)d_out;
    float* out_coord  = out;                                   // [N,3]
    float* cell_out   = out + (size_t)N * 3;                   // [B,6]
    float* out_logits = out + (size_t)N * 3 + (size_t)B * 6;   // [N,100]

    unsigned* wpk = (unsigned*)d_ws;                           // 114688 uints

    prep_kernel<<<448, 256, 0, stream>>>(w1a, w2a, wt, wc1, wl1, wpk);

    fused_kernel<<<1024, THREADS, 0, stream>>>(
        batch, N, t_emb, wpk,
        b1a, b2a, bc1, bl1,
        wc2, bc2, wl2, bl2, bt,
        out_coord, cell_out, (f32x4_n*)out_logits);
}